// Round 1
// baseline (202.872 us; speedup 1.0000x reference)
//
#include <hip/hip_runtime.h>
#include <stdint.h>

#define N_CODES 65536
#define CB_DIM 8
#define B_ROWS 16
#define X_COLS 2048
#define M_ROWS 4096            // 16*2048/8
#define RPB 8                  // rows per block in argmin kernel
#define THREADS 256

// workspace byte offsets (all 16B-aligned)
#define WS_SCALE 0             // 16 f32
#define WS_IDX   256           // 4096 i32
#define WS_U     16640         // 32768 f32  (u = x/scale, flat)
#define WS_SUMS  147712        // 65536*8 f32
#define WS_CNT   2244864       // 65536 f32
// total ~2.4 MB

// ---------------- scale: per-row mean(|x|) ----------------
__global__ __launch_bounds__(256) void scale_kernel(const float* __restrict__ x,
                                                    float* __restrict__ scale) {
    int r = blockIdx.x;
    int tid = threadIdx.x;
    const float* xr = x + r * X_COLS;
    float s = 0.f;
    for (int j = tid; j < X_COLS; j += 256) s += fabsf(xr[j]);
    #pragma unroll
    for (int off = 32; off > 0; off >>= 1) s += __shfl_down(s, off, 64);
    __shared__ float ls[4];
    int wave = tid >> 6, lane = tid & 63;
    if (lane == 0) ls[wave] = s;
    __syncthreads();
    if (tid == 0) {
        float t = ls[0] + ls[1] + ls[2] + ls[3];
        scale[r] = t / (float)X_COLS;
    }
}

// ---------------- argmin over 65536 codes, 8 rows per block ----------------
__global__ __launch_bounds__(256) void argmin_kernel(const float* __restrict__ x,
                                                     const float* __restrict__ cb,
                                                     const float* __restrict__ scale,
                                                     int* __restrict__ indices,
                                                     float* __restrict__ uout) {
    __shared__ float u_sh[RPB * CB_DIM];               // 64 floats
    int tid = threadIdx.x;
    int m0 = blockIdx.x * RPB;

    if (tid < RPB * CB_DIM) {
        int r = tid >> 3, k = tid & 7;
        int m = m0 + r;
        int xr = m >> 8;                               // row of x (2048/8=256 groups/row)
        int col = (m & 255) * 8 + k;
        float u = x[xr * X_COLS + col] / scale[xr];
        u_sh[tid] = u;
        uout[m * CB_DIM + k] = u;                      // persist u for segment-sum pass
    }
    __syncthreads();

    float nu[RPB][CB_DIM];                             // negated u, so dist = fma(nu,c,acc)
    #pragma unroll
    for (int r = 0; r < RPB; r++)
        #pragma unroll
        for (int k = 0; k < CB_DIM; k++)
            nu[r][k] = -u_sh[r * CB_DIM + k];

    float best[RPB];
    int   bidx[RPB];
    #pragma unroll
    for (int r = 0; r < RPB; r++) { best[r] = 3.4e38f; bidx[r] = 0; }

    // each thread: codes tid, tid+256, ... (ascending => strict < keeps lowest idx on tie)
    for (int n = tid; n < N_CODES; n += THREADS) {
        const float4* cp = (const float4*)(cb + (size_t)n * CB_DIM);
        float4 c0 = cp[0];
        float4 c1 = cp[1];
        // 0.5*||c||^2  (exact halving; argmin-equivalent to ||c||^2 - 2 u.c)
        float hn = c0.x * c0.x;
        hn = fmaf(c0.y, c0.y, hn);
        hn = fmaf(c0.z, c0.z, hn);
        hn = fmaf(c0.w, c0.w, hn);
        hn = fmaf(c1.x, c1.x, hn);
        hn = fmaf(c1.y, c1.y, hn);
        hn = fmaf(c1.z, c1.z, hn);
        hn = fmaf(c1.w, c1.w, hn);
        hn *= 0.5f;
        #pragma unroll
        for (int r = 0; r < RPB; r++) {
            float d = hn;
            d = fmaf(nu[r][0], c0.x, d);
            d = fmaf(nu[r][1], c0.y, d);
            d = fmaf(nu[r][2], c0.z, d);
            d = fmaf(nu[r][3], c0.w, d);
            d = fmaf(nu[r][4], c1.x, d);
            d = fmaf(nu[r][5], c1.y, d);
            d = fmaf(nu[r][6], c1.z, d);
            d = fmaf(nu[r][7], c1.w, d);
            if (d < best[r]) { best[r] = d; bidx[r] = n; }
        }
    }

    // cross-thread reduce: pack (sortable(dist) << 32) | idx, u64-min gives
    // min-dist with lowest-index tie-break (np.argmin semantics)
    __shared__ unsigned long long red[RPB][THREADS];   // 16 KB
    #pragma unroll
    for (int r = 0; r < RPB; r++) {
        unsigned int b = __float_as_uint(best[r]);
        unsigned int k = b ^ ((unsigned int)((int)b >> 31) | 0x80000000u);
        red[r][tid] = ((unsigned long long)k << 32) | (unsigned int)bidx[r];
    }
    for (int s = THREADS / 2; s > 0; s >>= 1) {
        __syncthreads();
        if (tid < s) {
            #pragma unroll
            for (int r = 0; r < RPB; r++) {
                unsigned long long a = red[r][tid], c = red[r][tid + s];
                if (c < a) red[r][tid] = c;
            }
        }
    }
    __syncthreads();
    if (tid < RPB) {
        indices[m0 + tid] = (int)(red[tid][0] & 0xFFFFFFFFull);
    }
}

// ---------------- zero sums/counts at selected codes only ----------------
__global__ __launch_bounds__(256) void zero_kernel(const int* __restrict__ indices,
                                                   float* __restrict__ sums,
                                                   float* __restrict__ counts) {
    int m = blockIdx.x * blockDim.x + threadIdx.x;
    if (m < M_ROWS) {
        int idx = indices[m];
        counts[idx] = 0.f;                             // benign races: all write 0
        float4 z = make_float4(0.f, 0.f, 0.f, 0.f);
        float4* sp = (float4*)(sums + (size_t)idx * CB_DIM);
        sp[0] = z;
        sp[1] = z;
    }
}

// ---------------- segment-sum via atomics ----------------
__global__ __launch_bounds__(256) void accum_kernel(const int* __restrict__ indices,
                                                    const float* __restrict__ u,
                                                    float* __restrict__ sums,
                                                    float* __restrict__ counts) {
    int m = blockIdx.x * blockDim.x + threadIdx.x;
    if (m < M_ROWS) {
        int idx = indices[m];
        atomicAdd(&counts[idx], 1.0f);
        #pragma unroll
        for (int k = 0; k < CB_DIM; k++)
            atomicAdd(&sums[(size_t)idx * CB_DIM + k], u[m * CB_DIM + k]);
    }
}

// ---------------- gather + rescale ----------------
__global__ __launch_bounds__(256) void gather_kernel(const int* __restrict__ indices,
                                                     const float* __restrict__ sums,
                                                     const float* __restrict__ counts,
                                                     const float* __restrict__ scale,
                                                     float* __restrict__ out) {
    int e = blockIdx.x * blockDim.x + threadIdx.x;     // 0..32767
    if (e < B_ROWS * X_COLS) {
        int m = e >> 3, k = e & 7;
        int idx = indices[m];
        float c = counts[idx];
        c = c < 1.f ? 1.f : c;
        out[e] = scale[e >> 11] * (sums[(size_t)idx * CB_DIM + k] / c);
    }
}

extern "C" void kernel_launch(void* const* d_in, const int* in_sizes, int n_in,
                              void* d_out, int out_size, void* d_ws, size_t ws_size,
                              hipStream_t stream) {
    const float* x  = (const float*)d_in[0];           // [16,2048]
    const float* cb = (const float*)d_in[1];           // [65536,8]
    char* ws = (char*)d_ws;
    float* scale   = (float*)(ws + WS_SCALE);
    int*   indices = (int*)(ws + WS_IDX);
    float* u       = (float*)(ws + WS_U);
    float* sums    = (float*)(ws + WS_SUMS);
    float* counts  = (float*)(ws + WS_CNT);
    float* out     = (float*)d_out;

    scale_kernel <<<B_ROWS, 256, 0, stream>>>(x, scale);
    argmin_kernel<<<M_ROWS / RPB, 256, 0, stream>>>(x, cb, scale, indices, u);
    zero_kernel  <<<M_ROWS / 256, 256, 0, stream>>>(indices, sums, counts);
    accum_kernel <<<M_ROWS / 256, 256, 0, stream>>>(indices, u, sums, counts);
    gather_kernel<<<(B_ROWS * X_COLS) / 256, 256, 0, stream>>>(indices, sums, counts, scale, out);
}

// Round 2
// 179.862 us; speedup vs baseline: 1.1279x; 1.1279x over previous
//
#include <hip/hip_runtime.h>
#include <stdint.h>

#define N_CODES 65536
#define CB_DIM 8
#define B_ROWS 16
#define X_COLS 2048
#define M_ROWS 4096            // 16*2048/8
#define RPB 8                  // rows per block in argmin kernel
#define THREADS 256

// workspace byte offsets (all 16B-aligned)
#define WS_SCALE 0             // 16 f32
#define WS_IDX   256           // 4096 i32
#define WS_U     16640         // 32768 f32  (u = x/scale, flat)
#define WS_SUMS  147712        // 65536*8 f32
#define WS_CNT   2244864       // 65536 f32

// ---------------- fused: scale + argmin + zero-selected ----------------
// launch_bounds(256,2): grid is 512 blocks = 2 blocks/CU anyway; allow up to
// 256 VGPRs so nu2[8][8] + best/bidx stay register-resident (round-1 failure:
// default bounds capped VGPR=48 -> inner-loop LDS rereads -> VALUBusy 47%).
__global__ __launch_bounds__(256, 2) void argmin_kernel(const float* __restrict__ x,
                                                        const float* __restrict__ cb,
                                                        float* __restrict__ scale_out,
                                                        int* __restrict__ indices,
                                                        float* __restrict__ uout,
                                                        float* __restrict__ sums,
                                                        float* __restrict__ counts) {
    int tid = threadIdx.x;
    int m0 = blockIdx.x * RPB;
    int xr = m0 >> 8;                                  // this block's x row (8 rows share it)

    // ---- per-block scale for x-row xr: mean(|x[xr,:]|) over 2048 cols ----
    const float4* xv = (const float4*)(x + xr * X_COLS);
    float4 a0 = xv[tid];
    float4 a1 = xv[tid + 256];
    float s = fabsf(a0.x) + fabsf(a0.y) + fabsf(a0.z) + fabsf(a0.w)
            + fabsf(a1.x) + fabsf(a1.y) + fabsf(a1.z) + fabsf(a1.w);
    #pragma unroll
    for (int off = 32; off > 0; off >>= 1) s += __shfl_down(s, off, 64);
    __shared__ float ls[4];
    __shared__ float scale_sh;
    int wave = tid >> 6, lane = tid & 63;
    if (lane == 0) ls[wave] = s;
    __syncthreads();
    if (tid == 0) {
        float t = (ls[0] + ls[1] + ls[2] + ls[3]) * (1.0f / (float)X_COLS);
        scale_sh = t;
        if ((blockIdx.x & 31) == 0) scale_out[xr] = t;  // persist for gather
    }
    __syncthreads();
    float scale = scale_sh;

    // ---- u for this block's 8 rows (64 consecutive elements of x-row) ----
    __shared__ float u_sh[RPB * CB_DIM];
    if (tid < RPB * CB_DIM) {
        int col = (m0 & 255) * CB_DIM + tid;
        float u = x[xr * X_COLS + col] / scale;
        u_sh[tid] = u;
        uout[m0 * CB_DIM + tid] = u;                   // persist for accum pass
    }
    __syncthreads();

    // -2*u in registers: d = ||c||^2 - 2 u.c  (argmin-equivalent, exact x2)
    float nu2[RPB][CB_DIM];
    #pragma unroll
    for (int r = 0; r < RPB; r++)
        #pragma unroll
        for (int k = 0; k < CB_DIM; k++)
            nu2[r][k] = -2.0f * u_sh[r * CB_DIM + k];

    float best[RPB];
    int   bidx[RPB];
    #pragma unroll
    for (int r = 0; r < RPB; r++) { best[r] = 3.4e38f; bidx[r] = 0; }

    // each thread: codes tid, tid+256, ... (ascending => strict < keeps lowest idx on tie)
    for (int n = tid; n < N_CODES; n += THREADS) {
        const float4* cp = (const float4*)(cb + (size_t)n * CB_DIM);
        float4 c0 = cp[0];
        float4 c1 = cp[1];
        float hn = c0.x * c0.x;
        hn = fmaf(c0.y, c0.y, hn);
        hn = fmaf(c0.z, c0.z, hn);
        hn = fmaf(c0.w, c0.w, hn);
        hn = fmaf(c1.x, c1.x, hn);
        hn = fmaf(c1.y, c1.y, hn);
        hn = fmaf(c1.z, c1.z, hn);
        hn = fmaf(c1.w, c1.w, hn);
        #pragma unroll
        for (int r = 0; r < RPB; r++) {
            float d = hn;
            d = fmaf(nu2[r][0], c0.x, d);
            d = fmaf(nu2[r][1], c0.y, d);
            d = fmaf(nu2[r][2], c0.z, d);
            d = fmaf(nu2[r][3], c0.w, d);
            d = fmaf(nu2[r][4], c1.x, d);
            d = fmaf(nu2[r][5], c1.y, d);
            d = fmaf(nu2[r][6], c1.z, d);
            d = fmaf(nu2[r][7], c1.w, d);
            if (d < best[r]) { best[r] = d; bidx[r] = n; }
        }
    }

    // cross-thread reduce: pack (sortable(dist) << 32) | idx; u64-min gives
    // min-dist with lowest-index tie-break (np.argmin first-occurrence)
    __shared__ unsigned long long red[RPB][THREADS];   // 16 KB
    #pragma unroll
    for (int r = 0; r < RPB; r++) {
        unsigned int b = __float_as_uint(best[r]);
        unsigned int k = b ^ ((unsigned int)((int)b >> 31) | 0x80000000u);
        red[r][tid] = ((unsigned long long)k << 32) | (unsigned int)bidx[r];
    }
    for (int t = THREADS / 2; t > 0; t >>= 1) {
        __syncthreads();
        if (tid < t) {
            #pragma unroll
            for (int r = 0; r < RPB; r++) {
                unsigned long long a = red[r][tid], c = red[r][tid + t];
                if (c < a) red[r][tid] = c;
            }
        }
    }
    __syncthreads();

    // write indices + zero sums/counts at the selected codes (kernel boundary
    // orders these zeros before accum; cross-block duplicate zeros are benign)
    if (tid < RPB) {
        int idx = (int)(red[tid][0] & 0xFFFFFFFFull);
        indices[m0 + tid] = idx;
        counts[idx] = 0.f;
        float4 z = make_float4(0.f, 0.f, 0.f, 0.f);
        float4* sp = (float4*)(sums + (size_t)idx * CB_DIM);
        sp[0] = z;
        sp[1] = z;
    }
}

// ---------------- segment-sum via atomics ----------------
__global__ __launch_bounds__(256) void accum_kernel(const int* __restrict__ indices,
                                                    const float* __restrict__ u,
                                                    float* __restrict__ sums,
                                                    float* __restrict__ counts) {
    int m = blockIdx.x * blockDim.x + threadIdx.x;
    if (m < M_ROWS) {
        int idx = indices[m];
        atomicAdd(&counts[idx], 1.0f);
        #pragma unroll
        for (int k = 0; k < CB_DIM; k++)
            atomicAdd(&sums[(size_t)idx * CB_DIM + k], u[m * CB_DIM + k]);
    }
}

// ---------------- gather + rescale ----------------
__global__ __launch_bounds__(256) void gather_kernel(const int* __restrict__ indices,
                                                     const float* __restrict__ sums,
                                                     const float* __restrict__ counts,
                                                     const float* __restrict__ scale,
                                                     float* __restrict__ out) {
    int e = blockIdx.x * blockDim.x + threadIdx.x;     // 0..32767
    if (e < B_ROWS * X_COLS) {
        int m = e >> 3, k = e & 7;
        int idx = indices[m];
        float c = counts[idx];
        c = c < 1.f ? 1.f : c;
        out[e] = scale[e >> 11] * (sums[(size_t)idx * CB_DIM + k] / c);
    }
}

extern "C" void kernel_launch(void* const* d_in, const int* in_sizes, int n_in,
                              void* d_out, int out_size, void* d_ws, size_t ws_size,
                              hipStream_t stream) {
    const float* x  = (const float*)d_in[0];           // [16,2048]
    const float* cb = (const float*)d_in[1];           // [65536,8]
    char* ws = (char*)d_ws;
    float* scale   = (float*)(ws + WS_SCALE);
    int*   indices = (int*)(ws + WS_IDX);
    float* u       = (float*)(ws + WS_U);
    float* sums    = (float*)(ws + WS_SUMS);
    float* counts  = (float*)(ws + WS_CNT);
    float* out     = (float*)d_out;

    argmin_kernel<<<M_ROWS / RPB, 256, 0, stream>>>(x, cb, scale, indices, u, sums, counts);
    accum_kernel <<<M_ROWS / 256, 256, 0, stream>>>(indices, u, sums, counts);
    gather_kernel<<<(B_ROWS * X_COLS) / 256, 256, 0, stream>>>(indices, sums, counts, scale, out);
}

// Round 3
// 154.544 us; speedup vs baseline: 1.3127x; 1.1638x over previous
//
#include <hip/hip_runtime.h>
#include <stdint.h>

#define N_CODES 65536
#define CB_DIM 8
#define B_ROWS 16
#define X_COLS 2048
#define M_ROWS 4096            // 16*2048/8
#define RPB 8                  // rows per block in argmin kernel
#define THREADS 256

// workspace byte offsets (all 16B-aligned)
#define WS_SCALE 0             // 16 f32
#define WS_IDX   256           // 4096 i32
#define WS_U     16640         // 32768 f32  (u = x/scale, flat)
#define WS_SUMS  147712        // 65536*8 f32
#define WS_CNT   2244864       // 65536 f32

// block-uniform float -> SGPR
__device__ __forceinline__ float rfl(float x) {
    return __uint_as_float(__builtin_amdgcn_readfirstlane(__float_as_uint(x)));
}

// distance + min-track for one code against 8 SGPR-resident rows
#define CODE_BODY(C0, C1, NIDX)                                            \
    {                                                                      \
        float hn = (C0).x * (C0).x;                                        \
        hn = fmaf((C0).y, (C0).y, hn);                                     \
        hn = fmaf((C0).z, (C0).z, hn);                                     \
        hn = fmaf((C0).w, (C0).w, hn);                                     \
        hn = fmaf((C1).x, (C1).x, hn);                                     \
        hn = fmaf((C1).y, (C1).y, hn);                                     \
        hn = fmaf((C1).z, (C1).z, hn);                                     \
        hn = fmaf((C1).w, (C1).w, hn);                                     \
        _Pragma("unroll")                                                  \
        for (int r = 0; r < RPB; r++) {                                    \
            float d = hn;                                                  \
            d = fmaf(nu[r * 8 + 0], (C0).x, d);                            \
            d = fmaf(nu[r * 8 + 1], (C0).y, d);                            \
            d = fmaf(nu[r * 8 + 2], (C0).z, d);                            \
            d = fmaf(nu[r * 8 + 3], (C0).w, d);                            \
            d = fmaf(nu[r * 8 + 4], (C1).x, d);                            \
            d = fmaf(nu[r * 8 + 5], (C1).y, d);                            \
            d = fmaf(nu[r * 8 + 6], (C1).z, d);                            \
            d = fmaf(nu[r * 8 + 7], (C1).w, d);                            \
            if (d < best[r]) { best[r] = d; bidx[r] = (NIDX); }            \
        }                                                                  \
    }

// ---------------- fused: scale + argmin + zero-selected ----------------
__global__ __launch_bounds__(256, 2) void argmin_kernel(const float* __restrict__ x,
                                                        const float* __restrict__ cb,
                                                        float* __restrict__ scale_out,
                                                        int* __restrict__ indices,
                                                        float* __restrict__ uout,
                                                        float* __restrict__ sums,
                                                        float* __restrict__ counts) {
    int tid = threadIdx.x;
    int m0 = blockIdx.x * RPB;
    int xr = m0 >> 8;                                  // this block's x row

    // ---- per-block scale for x-row xr: mean(|x[xr,:]|) ----
    const float4* xv = (const float4*)(x + xr * X_COLS);
    float4 q0 = xv[tid];
    float4 q1 = xv[tid + 256];
    float s = fabsf(q0.x) + fabsf(q0.y) + fabsf(q0.z) + fabsf(q0.w)
            + fabsf(q1.x) + fabsf(q1.y) + fabsf(q1.z) + fabsf(q1.w);
    #pragma unroll
    for (int off = 32; off > 0; off >>= 1) s += __shfl_down(s, off, 64);
    __shared__ float ls[4];
    __shared__ float scale_sh;
    int wave = tid >> 6, lane = tid & 63;
    if (lane == 0) ls[wave] = s;
    __syncthreads();
    if (tid == 0) {
        float t = (ls[0] + ls[1] + ls[2] + ls[3]) * (1.0f / (float)X_COLS);
        scale_sh = t;
        if ((blockIdx.x & 31) == 0) scale_out[xr] = t;
    }
    __syncthreads();
    float scale = scale_sh;

    // ---- u for this block's 8 rows (64 consecutive x elements) ----
    __shared__ float u_sh[RPB * CB_DIM];
    if (tid < RPB * CB_DIM) {
        int col = (m0 & 255) * CB_DIM + tid;
        float u = x[xr * X_COLS + col] / scale;
        u_sh[tid] = u;
        uout[m0 * CB_DIM + tid] = u;
    }
    __syncthreads();

    // -2u into SGPRs (block-uniform -> readfirstlane). d = ||c||^2 - 2 u.c.
    // This guarantees no LDS rereads in the hot loop (round-2 failure:
    // compiler kept VGPR=52 and served nu2 from LDS; VALUBusy 51%).
    float nu[RPB * CB_DIM];
    #pragma unroll
    for (int i = 0; i < RPB * CB_DIM; i++) nu[i] = rfl(-2.0f * u_sh[i]);

    float best[RPB];
    int   bidx[RPB];
    #pragma unroll
    for (int r = 0; r < RPB; r++) { best[r] = 3.4e38f; bidx[r] = 0; }

    // ---- hot loop: 2 codes/iter, register double-prefetch ----
    const float4* cp = (const float4*)cb;
    float4 a0 = cp[2 * tid],             a1 = cp[2 * tid + 1];
    float4 b0 = cp[2 * (tid + THREADS)], b1 = cp[2 * (tid + THREADS) + 1];

    for (int n = tid; n < N_CODES; n += 2 * THREADS) {
        int np = n + 2 * THREADS; np = (np < N_CODES) ? np : tid;
        float4 pa0 = cp[2 * np], pa1 = cp[2 * np + 1];
        CODE_BODY(a0, a1, n)
        int nq = n + 3 * THREADS; nq = (nq < N_CODES) ? nq : tid;
        float4 pb0 = cp[2 * nq], pb1 = cp[2 * nq + 1];
        CODE_BODY(b0, b1, n + THREADS)
        a0 = pa0; a1 = pa1; b0 = pb0; b1 = pb1;
    }

    // ---- cross-thread reduce: (sortable(dist)<<32)|idx, u64-min ----
    __shared__ unsigned long long red[RPB][THREADS];   // 16 KB
    #pragma unroll
    for (int r = 0; r < RPB; r++) {
        unsigned int b = __float_as_uint(best[r]);
        unsigned int k = b ^ ((unsigned int)((int)b >> 31) | 0x80000000u);
        red[r][tid] = ((unsigned long long)k << 32) | (unsigned int)bidx[r];
    }
    for (int t = THREADS / 2; t > 0; t >>= 1) {
        __syncthreads();
        if (tid < t) {
            #pragma unroll
            for (int r = 0; r < RPB; r++) {
                unsigned long long a = red[r][tid], c = red[r][tid + t];
                if (c < a) red[r][tid] = c;
            }
        }
    }
    __syncthreads();

    // indices + zero sums/counts at selected codes (kernel boundary orders
    // the zeros before accum; duplicate zero-writes are benign)
    if (tid < RPB) {
        int idx = (int)(red[tid][0] & 0xFFFFFFFFull);
        indices[m0 + tid] = idx;
        counts[idx] = 0.f;
        float4 z = make_float4(0.f, 0.f, 0.f, 0.f);
        float4* sp = (float4*)(sums + (size_t)idx * CB_DIM);
        sp[0] = z;
        sp[1] = z;
    }
}

// ---------------- segment-sum via atomics ----------------
__global__ __launch_bounds__(256) void accum_kernel(const int* __restrict__ indices,
                                                    const float* __restrict__ u,
                                                    float* __restrict__ sums,
                                                    float* __restrict__ counts) {
    int m = blockIdx.x * blockDim.x + threadIdx.x;
    if (m < M_ROWS) {
        int idx = indices[m];
        atomicAdd(&counts[idx], 1.0f);
        #pragma unroll
        for (int k = 0; k < CB_DIM; k++)
            atomicAdd(&sums[(size_t)idx * CB_DIM + k], u[m * CB_DIM + k]);
    }
}

// ---------------- gather + rescale ----------------
__global__ __launch_bounds__(256) void gather_kernel(const int* __restrict__ indices,
                                                     const float* __restrict__ sums,
                                                     const float* __restrict__ counts,
                                                     const float* __restrict__ scale,
                                                     float* __restrict__ out) {
    int e = blockIdx.x * blockDim.x + threadIdx.x;     // 0..32767
    if (e < B_ROWS * X_COLS) {
        int m = e >> 3, k = e & 7;
        int idx = indices[m];
        float c = counts[idx];
        c = c < 1.f ? 1.f : c;
        out[e] = scale[e >> 11] * (sums[(size_t)idx * CB_DIM + k] / c);
    }
}

extern "C" void kernel_launch(void* const* d_in, const int* in_sizes, int n_in,
                              void* d_out, int out_size, void* d_ws, size_t ws_size,
                              hipStream_t stream) {
    const float* x  = (const float*)d_in[0];           // [16,2048]
    const float* cb = (const float*)d_in[1];           // [65536,8]
    char* ws = (char*)d_ws;
    float* scale   = (float*)(ws + WS_SCALE);
    int*   indices = (int*)(ws + WS_IDX);
    float* u       = (float*)(ws + WS_U);
    float* sums    = (float*)(ws + WS_SUMS);
    float* counts  = (float*)(ws + WS_CNT);
    float* out     = (float*)d_out;

    argmin_kernel<<<M_ROWS / RPB, 256, 0, stream>>>(x, cb, scale, indices, u, sums, counts);
    accum_kernel <<<M_ROWS / 256, 256, 0, stream>>>(indices, u, sums, counts);
    gather_kernel<<<(B_ROWS * X_COLS) / 256, 256, 0, stream>>>(indices, sums, counts, scale, out);
}

// Round 4
// 138.710 us; speedup vs baseline: 1.4626x; 1.1141x over previous
//
#include <hip/hip_runtime.h>
#include <stdint.h>

#define N_CODES 65536
#define CB_DIM 8
#define B_ROWS 16
#define X_COLS 2048
#define M_ROWS 4096            // 16*2048/8
#define RPB 8                  // rows per block in argmin kernel
#define THREADS 256

// workspace byte offsets (all 16B-aligned)
#define WS_SCALE 0             // 16 f32
#define WS_IDX   256           // 4096 i32
#define WS_U     16640         // 32768 f32  (u = x/scale, flat)
#define WS_SUMS  147712        // 65536*8 f32
#define WS_CNT   2244864       // 65536 f32

// distance + min-track for one code against 8 register-resident rows
#define CODE_BODY(C0, C1, NIDX)                                            \
    {                                                                      \
        float hn = (C0).x * (C0).x;                                        \
        hn = fmaf((C0).y, (C0).y, hn);                                     \
        hn = fmaf((C0).z, (C0).z, hn);                                     \
        hn = fmaf((C0).w, (C0).w, hn);                                     \
        hn = fmaf((C1).x, (C1).x, hn);                                     \
        hn = fmaf((C1).y, (C1).y, hn);                                     \
        hn = fmaf((C1).z, (C1).z, hn);                                     \
        hn = fmaf((C1).w, (C1).w, hn);                                     \
        _Pragma("unroll")                                                  \
        for (int r = 0; r < RPB; r++) {                                    \
            float d = hn;                                                  \
            d = fmaf(nu[r * 8 + 0], (C0).x, d);                            \
            d = fmaf(nu[r * 8 + 1], (C0).y, d);                            \
            d = fmaf(nu[r * 8 + 2], (C0).z, d);                            \
            d = fmaf(nu[r * 8 + 3], (C0).w, d);                            \
            d = fmaf(nu[r * 8 + 4], (C1).x, d);                            \
            d = fmaf(nu[r * 8 + 5], (C1).y, d);                            \
            d = fmaf(nu[r * 8 + 6], (C1).z, d);                            \
            d = fmaf(nu[r * 8 + 7], (C1).w, d);                            \
            if (d < best[r]) { best[r] = d; bidx[r] = (NIDX); }            \
        }                                                                  \
    }

// ---------------- fused: scale + argmin + zero-selected ----------------
__global__ __launch_bounds__(256, 2) void argmin_kernel(const float* __restrict__ x,
                                                        const float* __restrict__ cb,
                                                        float* __restrict__ scale_out,
                                                        int* __restrict__ indices,
                                                        float* __restrict__ uout,
                                                        float* __restrict__ sums,
                                                        float* __restrict__ counts) {
    int tid = threadIdx.x;
    int m0 = blockIdx.x * RPB;
    int xr = m0 >> 8;                                  // this block's x row

    // ---- per-block scale for x-row xr: mean(|x[xr,:]|) ----
    const float4* xv = (const float4*)(x + xr * X_COLS);
    float4 q0 = xv[tid];
    float4 q1 = xv[tid + 256];
    float s = fabsf(q0.x) + fabsf(q0.y) + fabsf(q0.z) + fabsf(q0.w)
            + fabsf(q1.x) + fabsf(q1.y) + fabsf(q1.z) + fabsf(q1.w);
    #pragma unroll
    for (int off = 32; off > 0; off >>= 1) s += __shfl_down(s, off, 64);
    __shared__ float ls[4];
    __shared__ float scale_sh;
    int wave = tid >> 6, lane = tid & 63;
    if (lane == 0) ls[wave] = s;
    __syncthreads();
    if (tid == 0) {
        float t = (ls[0] + ls[1] + ls[2] + ls[3]) * (1.0f / (float)X_COLS);
        scale_sh = t;
        if ((blockIdx.x & 31) == 0) scale_out[xr] = t;
    }
    __syncthreads();
    float scale = scale_sh;

    // ---- u for this block's 8 rows (64 consecutive x elements) ----
    __shared__ float u_sh[RPB * CB_DIM];
    if (tid < RPB * CB_DIM) {
        int col = (m0 & 255) * CB_DIM + tid;
        float u = x[xr * X_COLS + col] / scale;
        u_sh[tid] = u;
        uout[m0 * CB_DIM + tid] = u;
    }
    __syncthreads();

    // -2u, PINNED into VGPRs via asm black box. Round-3 failure: compiler
    // rematerialized (ds_read + v_mul) each use inside the hot loop -> 2x
    // VALU instrs. The empty volatile asm makes the value opaque: it must
    // stay register-resident for all 128 loop iterations.
    float nu[RPB * CB_DIM];
    #pragma unroll
    for (int i = 0; i < RPB * CB_DIM; i++) {
        nu[i] = -2.0f * u_sh[i];
        asm volatile("" : "+v"(nu[i]));
    }

    float best[RPB];
    int   bidx[RPB];
    #pragma unroll
    for (int r = 0; r < RPB; r++) { best[r] = 3.4e38f; bidx[r] = 0; }

    // ---- hot loop: 2 codes/iter, register double-prefetch, peeled tail ----
    // 128 iterations total; first 127 have in-range prefetch (n+768 <= 65535),
    // so no wrap cndmask in the hot path.
    const float4* cp = (const float4*)cb;
    float4 a0 = cp[2 * tid],             a1 = cp[2 * tid + 1];
    float4 b0 = cp[2 * (tid + THREADS)], b1 = cp[2 * (tid + THREADS) + 1];

    int n = tid;
    for (int k = 0; k < 127; k++, n += 2 * THREADS) {
        float4 pa0 = cp[2 * (n + 2 * THREADS)], pa1 = cp[2 * (n + 2 * THREADS) + 1];
        CODE_BODY(a0, a1, n)
        float4 pb0 = cp[2 * (n + 3 * THREADS)], pb1 = cp[2 * (n + 3 * THREADS) + 1];
        CODE_BODY(b0, b1, n + THREADS)
        a0 = pa0; a1 = pa1; b0 = pb0; b1 = pb1;
    }
    CODE_BODY(a0, a1, n)
    CODE_BODY(b0, b1, n + THREADS)

    // ---- cross-thread reduce: (sortable(dist)<<32)|idx, u64-min ----
    __shared__ unsigned long long red[RPB][THREADS];   // 16 KB
    #pragma unroll
    for (int r = 0; r < RPB; r++) {
        unsigned int b = __float_as_uint(best[r]);
        unsigned int k = b ^ ((unsigned int)((int)b >> 31) | 0x80000000u);
        red[r][tid] = ((unsigned long long)k << 32) | (unsigned int)bidx[r];
    }
    for (int t = THREADS / 2; t > 0; t >>= 1) {
        __syncthreads();
        if (tid < t) {
            #pragma unroll
            for (int r = 0; r < RPB; r++) {
                unsigned long long a = red[r][tid], c = red[r][tid + t];
                if (c < a) red[r][tid] = c;
            }
        }
    }
    __syncthreads();

    // indices + zero sums/counts at selected codes (kernel boundary orders
    // the zeros before accum; duplicate zero-writes are benign)
    if (tid < RPB) {
        int idx = (int)(red[tid][0] & 0xFFFFFFFFull);
        indices[m0 + tid] = idx;
        counts[idx] = 0.f;
        float4 z = make_float4(0.f, 0.f, 0.f, 0.f);
        float4* sp = (float4*)(sums + (size_t)idx * CB_DIM);
        sp[0] = z;
        sp[1] = z;
    }
}

// ---------------- segment-sum via atomics ----------------
__global__ __launch_bounds__(256) void accum_kernel(const int* __restrict__ indices,
                                                    const float* __restrict__ u,
                                                    float* __restrict__ sums,
                                                    float* __restrict__ counts) {
    int m = blockIdx.x * blockDim.x + threadIdx.x;
    if (m < M_ROWS) {
        int idx = indices[m];
        atomicAdd(&counts[idx], 1.0f);
        #pragma unroll
        for (int k = 0; k < CB_DIM; k++)
            atomicAdd(&sums[(size_t)idx * CB_DIM + k], u[m * CB_DIM + k]);
    }
}

// ---------------- gather + rescale ----------------
__global__ __launch_bounds__(256) void gather_kernel(const int* __restrict__ indices,
                                                     const float* __restrict__ sums,
                                                     const float* __restrict__ counts,
                                                     const float* __restrict__ scale,
                                                     float* __restrict__ out) {
    int e = blockIdx.x * blockDim.x + threadIdx.x;     // 0..32767
    if (e < B_ROWS * X_COLS) {
        int m = e >> 3, k = e & 7;
        int idx = indices[m];
        float c = counts[idx];
        c = c < 1.f ? 1.f : c;
        out[e] = scale[e >> 11] * (sums[(size_t)idx * CB_DIM + k] / c);
    }
}

extern "C" void kernel_launch(void* const* d_in, const int* in_sizes, int n_in,
                              void* d_out, int out_size, void* d_ws, size_t ws_size,
                              hipStream_t stream) {
    const float* x  = (const float*)d_in[0];           // [16,2048]
    const float* cb = (const float*)d_in[1];           // [65536,8]
    char* ws = (char*)d_ws;
    float* scale   = (float*)(ws + WS_SCALE);
    int*   indices = (int*)(ws + WS_IDX);
    float* u       = (float*)(ws + WS_U);
    float* sums    = (float*)(ws + WS_SUMS);
    float* counts  = (float*)(ws + WS_CNT);
    float* out     = (float*)d_out;

    argmin_kernel<<<M_ROWS / RPB, 256, 0, stream>>>(x, cb, scale, indices, u, sums, counts);
    accum_kernel <<<M_ROWS / 256, 256, 0, stream>>>(indices, u, sums, counts);
    gather_kernel<<<(B_ROWS * X_COLS) / 256, 256, 0, stream>>>(indices, sums, counts, scale, out);
}